// Round 1
// baseline (208.488 us; speedup 1.0000x reference)
//
#include <hip/hip_runtime.h>
#include <stdint.h>

typedef unsigned long long u64;
typedef unsigned int u32;

#define KNN_K 16
#define SPLITS 16
#define QBLK 16

// order-preserving float->uint map (handles tiny negative d2 from cancellation)
__device__ __forceinline__ u32 fkey(float d) {
  u32 s = __float_as_uint(d);
  u32 m = (u32)((int32_t)s >> 31) | 0x80000000u;
  return s ^ m;
}

__device__ __forceinline__ void ce(u64 &a, u64 &b) {
  u64 x = a, y = b;
  bool lt = x < y;
  a = lt ? x : y;
  b = lt ? y : x;
}

__global__ void prep_pack(const float* __restrict__ pc, float4* __restrict__ pp,
                          int B, int N) {
  int i = blockIdx.x * blockDim.x + threadIdx.x;
  if (i >= B * N) return;
  int b = i / N, n = i - b * N;
  float x = pc[(b * 3 + 0) * N + n];
  float y = pc[(b * 3 + 1) * N + n];
  float z = pc[(b * 3 + 2) * N + n];
  // numpy-order sum of squares, no contraction
  float pn = __fadd_rn(__fadd_rn(__fmul_rn(x, x), __fmul_rn(y, y)), __fmul_rn(z, z));
  pp[i] = make_float4(x, y, z, pn);
}

template <bool PACKED>
__global__ __launch_bounds__(256) void knn_project(
    const float* __restrict__ pc,    // (B,3,N)
    const float* __restrict__ qc,    // (B,3,M)
    const float* __restrict__ temp,  // scalar
    const float4* __restrict__ pp,   // packed (B,N): x,y,z,|p|^2
    float* __restrict__ out,         // (B,3,M)
    int B, int N, int M) {
  __shared__ u64 lists[SPLITS][KNN_K][QBLK];  // 32 KiB

  const int C = N / SPLITS;  // points per split chunk
  int blocksPerB = M / QBLK;
  int b = blockIdx.x / blocksPerB;
  int qb = (blockIdx.x % blocksPerB) * QBLK;
  int t = threadIdx.x;
  int qi = t & (QBLK - 1);
  int s = t >> 4;
  int q = qb + qi;

  // query coords + |q|^2 (numpy order, no contraction)
  float qx = qc[(b * 3 + 0) * M + q];
  float qy = qc[(b * 3 + 1) * M + q];
  float qz = qc[(b * 3 + 2) * M + q];
  float qn = __fadd_rn(__fadd_rn(__fmul_rn(qx, qx), __fmul_rn(qy, qy)),
                       __fmul_rn(qz, qz));

  u64 best[16];
#pragma unroll
  for (int i = 0; i < 16; ++i) best[i] = ~0ull;

  int cbase = s * C;
#pragma unroll 1
  for (int g = 0; g < C; g += 16) {
    u64 fresh[16];
#pragma unroll
    for (int j = 0; j < 16; ++j) {
      int n = cbase + g + j;
      float px, py, pz, pn;
      if (PACKED) {
        float4 v = pp[b * N + n];
        px = v.x; py = v.y; pz = v.z; pn = v.w;
      } else {
        px = pc[(b * 3 + 0) * N + n];
        py = pc[(b * 3 + 1) * N + n];
        pz = pc[(b * 3 + 2) * N + n];
        pn = __fadd_rn(__fadd_rn(__fmul_rn(px, px), __fmul_rn(py, py)),
                       __fmul_rn(pz, pz));
      }
      // inner = ((qx*px + qy*py) + qz*pz), numpy order, no contraction
      float inner = __fadd_rn(__fadd_rn(__fmul_rn(qx, px), __fmul_rn(qy, py)),
                              __fmul_rn(qz, pz));
      // d2 = (qn + pn) - 2*inner  (2*inner is exact; single final rounding)
      float d2 = __fsub_rn(__fadd_rn(qn, pn), __fmul_rn(2.0f, inner));
      fresh[j] = ((u64)fkey(d2) << 32) | (u32)n;
    }
    // bitonic sort fresh ascending (compile-time indices throughout)
#pragma unroll
    for (int k = 2; k <= 16; k <<= 1) {
#pragma unroll
      for (int jj = k >> 1; jj > 0; jj >>= 1) {
#pragma unroll
        for (int i = 0; i < 16; ++i) {
          int l = i ^ jj;
          if (l > i) {
            if ((i & k) == 0) ce(fresh[i], fresh[l]);
            else              ce(fresh[l], fresh[i]);
          }
        }
      }
    }
    // partial bitonic merge: best <- lowest 16 of (best asc, fresh asc)
#pragma unroll
    for (int i = 0; i < 16; ++i) {
      u64 a = best[i], f = fresh[15 - i];
      best[i] = a < f ? a : f;
    }
#pragma unroll
    for (int jj = 8; jj > 0; jj >>= 1) {
#pragma unroll
      for (int i = 0; i < 16; ++i) {
        int l = i ^ jj;
        if (l > i) ce(best[i], best[l]);
      }
    }
  }

  // publish per-split sorted lists
#pragma unroll
  for (int i = 0; i < 16; ++i) lists[s][i][qi] = best[i];
  __syncthreads();

  // tree-merge across splits: h = 8,4,2,1
  for (int h = SPLITS / 2; h >= 1; h >>= 1) {
    if (s < h) {
      u64 m2[16];
#pragma unroll
      for (int i = 0; i < 16; ++i) {
        u64 a = lists[s][i][qi];
        u64 f = lists[s + h][15 - i][qi];
        m2[i] = a < f ? a : f;
      }
#pragma unroll
      for (int jj = 8; jj > 0; jj >>= 1) {
#pragma unroll
        for (int i = 0; i < 16; ++i) {
          int l = i ^ jj;
          if (l > i) ce(m2[i], m2[l]);
        }
      }
#pragma unroll
      for (int i = 0; i < 16; ++i) lists[s][i][qi] = m2[i];
    }
    __syncthreads();
  }

  // finisher: lanes 0..15 (s==0, qi==t) own one query each; qx/qy/qz valid
  if (t < QBLK) {
    float Tv = temp[0];
    float sigma = fmaxf(Tv * Tv, 1e-4f);
    float inv = 1.0f / (sigma + 1e-8f);
    float accx = 0.f, accy = 0.f, accz = 0.f, Z = 0.f;
    float m0 = 0.f;
#pragma unroll
    for (int j = 0; j < 16; ++j) {
      u64 kk = lists[0][j][t];
      int n = (int)(u32)kk;
      float px = pc[(b * 3 + 0) * N + n];
      float py = pc[(b * 3 + 1) * N + n];
      float pz = pc[(b * 3 + 2) * N + n];
      float dx = px - qx, dy = py - qy, dz = pz - qz;
      float d2 = fmaf(dz, dz, fmaf(dy, dy, dx * dx));  // exact-deltas form (weights)
      if (j == 0) m0 = d2;
      float e = __expf((m0 - d2) * inv);
      accx = fmaf(e, px, accx);
      accy = fmaf(e, py, accy);
      accz = fmaf(e, pz, accz);
      Z += e;
    }
    float rz = 1.0f / Z;
    out[(b * 3 + 0) * M + q] = accx * rz;
    out[(b * 3 + 1) * M + q] = accy * rz;
    out[(b * 3 + 2) * M + q] = accz * rz;
  }
}

extern "C" void kernel_launch(void* const* d_in, const int* in_sizes, int n_in,
                              void* d_out, int out_size, void* d_ws, size_t ws_size,
                              hipStream_t stream) {
  const int B = 8, N = 8192, M = 2048;
  const float* pc = (const float*)d_in[0];
  const float* qc = (const float*)d_in[1];
  const float* temp = (const float*)d_in[2];
  float* out = (float*)d_out;

  size_t packBytes = (size_t)B * N * sizeof(float4);
  bool packed = (ws_size >= packBytes) && (d_ws != nullptr);

  dim3 blk(256);
  if (packed) {
    prep_pack<<<dim3((B * N + 255) / 256), blk, 0, stream>>>(pc, (float4*)d_ws, B, N);
    knn_project<true><<<dim3(B * (M / QBLK)), blk, 0, stream>>>(
        pc, qc, temp, (const float4*)d_ws, out, B, N, M);
  } else {
    knn_project<false><<<dim3(B * (M / QBLK)), blk, 0, stream>>>(
        pc, qc, temp, nullptr, out, B, N, M);
  }
}

// Round 2
// 144.924 us; speedup vs baseline: 1.4386x; 1.4386x over previous
//
#include <hip/hip_runtime.h>
#include <stdint.h>

typedef unsigned long long u64;
typedef unsigned int u32;

// ---- cross-lane helpers (VALU-pipe, no LDS) ----
__device__ __forceinline__ float dpp_shr1_f(float v, int fill_bits) {
  // shift up by 1 within each row of 16; lane 0 of each row takes fill
  return __int_as_float(__builtin_amdgcn_update_dpp(
      fill_bits, __float_as_int(v), 0x111 /*row_shr:1*/, 0xF, 0xF, false));
}
__device__ __forceinline__ int dpp_shr1_i(int v) {
  return __builtin_amdgcn_update_dpp(0, v, 0x111, 0xF, 0xF, false);
}
__device__ __forceinline__ float rdlane_f(float v, int lane) {
  return __int_as_float(__builtin_amdgcn_readlane(__float_as_int(v), lane));
}

__global__ void prep_pack(const float* __restrict__ pc, float4* __restrict__ pp,
                          int B, int N) {
  int i = blockIdx.x * blockDim.x + threadIdx.x;
  if (i >= B * N) return;
  int b = i / N, n = i - b * N;
  float x = pc[(b * 3 + 0) * N + n];
  float y = pc[(b * 3 + 1) * N + n];
  float z = pc[(b * 3 + 2) * N + n];
  // numpy-order sum of squares, no contraction
  float pn = __fadd_rn(__fadd_rn(__fmul_rn(x, x), __fmul_rn(y, y)), __fmul_rn(z, z));
  pp[i] = make_float4(x, y, z, pn);
}

template <bool PACKED>
__global__ __launch_bounds__(256, 4) void knn_project2(
    const float* __restrict__ pc,    // (B,3,N)
    const float* __restrict__ qc,    // (B,3,M)
    const float* __restrict__ temp,  // scalar
    const float4* __restrict__ pp,   // packed (B,N): x,y,z,|p|^2
    float* __restrict__ out,         // (B,3,M)
    int B, int N, int M) {
  const float INF = __int_as_float(0x7f800000);
  const int NINF_BITS = (int)0xff800000;

  int tid = threadIdx.x;
  int lane = tid & 63;
  int grp = lane >> 5;   // which query of the wave's two
  int sub = lane & 31;   // point slot within a 32-point batch
  int qid = blockIdx.x * 8 + (tid >> 5);
  int b = qid / M;
  int q = qid - b * M;

  // query coords + |q|^2 (numpy order, no contraction)
  float qx = qc[(b * 3 + 0) * M + q];
  float qy = qc[(b * 3 + 1) * M + q];
  float qz = qc[(b * 3 + 2) * M + q];
  float qn = __fadd_rn(__fadd_rn(__fmul_rn(qx, qx), __fmul_rn(qy, qy)),
                       __fmul_rn(qz, qz));

  // distributed top-16: lane (l&15) of each 16-lane row holds entry (l&15),
  // sorted ascending; rows 0,1 mirror query A, rows 2,3 mirror query B.
  float val = INF;
  int idx = 0;
  float thresh = INF;

  const float4* __restrict__ base = pp + (size_t)b * N;
  const float* __restrict__ pcb = pc + (size_t)b * 3 * N;

  auto ldp = [&](int g) -> float4 {
    if (PACKED) {
      return base[g + sub];
    } else {
      int n = g + sub;
      float x = pcb[n], y = pcb[N + n], z = pcb[2 * N + n];
      float pn = __fadd_rn(__fadd_rn(__fmul_rn(x, x), __fmul_rn(y, y)),
                           __fmul_rn(z, z));
      return make_float4(x, y, z, pn);
    }
  };

  float4 cur = ldp(0);
#pragma unroll 1
  for (int g = 0; g < N; g += 32) {
    int gn = (g + 32 < N) ? (g + 32) : 0;
    float4 nxt = ldp(gn);  // prefetch; stays in flight across candidate loop

    // exact selection distance: (qn+pn) - 2*inner, numpy rounding order
    float inner = __fadd_rn(__fadd_rn(__fmul_rn(qx, cur.x), __fmul_rn(qy, cur.y)),
                            __fmul_rn(qz, cur.z));
    float d2 = __fsub_rn(__fadd_rn(qn, cur.w), __fmul_rn(2.0f, inner));

    u64 mask = __ballot(d2 < thresh);
    if (mask) {
      u32 mlo = (u32)mask;          // query A candidates (lanes 0-31)
      u32 mhi = (u32)(mask >> 32);  // query B candidates (lanes 32-63)
      while (mlo | mhi) {
        int sA = __ffs(mlo) - 1;    // lowest index first = top_k tie-break
        int sB = __ffs(mhi) - 1;
        int lA = (sA < 0) ? 0 : sA;
        int lB = (sB < 0) ? 32 : (sB + 32);
        float cA = rdlane_f(d2, lA);
        float cB = rdlane_f(d2, lB);
        if (sA < 0) cA = INF;       // uniform scalar selects
        if (sB < 0) cB = INF;
        int ciA = g + lA;
        int ciB = g + (lB - 32);
        float cv = grp ? cB : cA;   // per-lane gate by query group
        int ci = grp ? ciB : ciA;
        // distributed sorted insert (strict < keeps stability / tie-break)
        float pv = dpp_shr1_f(val, NINF_BITS);
        int pi = dpp_shr1_i(idx);
        bool p = cv < val;
        bool p2 = cv < pv;
        val = p ? (p2 ? pv : cv) : val;
        idx = p ? (p2 ? pi : ci) : idx;
        if (mlo) mlo &= mlo - 1;
        if (mhi) mhi &= mhi - 1;
      }
      // refresh per-group threshold = val[15] (stale within a batch is safe:
      // extra candidates insert as no-ops)
      float t0 = rdlane_f(val, 15);
      float t1 = rdlane_f(val, 47);
      thresh = grp ? t1 : t0;
    }
    cur = nxt;
  }

  // ---- finisher: lane (l&15) owns entry (l&15); mirrors compute redundantly ----
  float Tv = temp[0];
  float sigma = fmaxf(Tv * Tv, 1e-4f);
  float inv = 1.0f / (sigma + 1e-8f);
  int n = idx;
  float px = pcb[n], py = pcb[N + n], pz = pcb[2 * N + n];
  float dx = px - qx, dy = py - qy, dz = pz - qz;
  float d2w = fmaf(dz, dz, fmaf(dy, dy, dx * dx));  // exact-deltas form (weights)
  float m0 = grp ? rdlane_f(d2w, 32) : rdlane_f(d2w, 0);  // entry 0 = nearest
  float e = __expf((m0 - d2w) * inv);
  float sx = e * px, sy = e * py, sz = e * pz, sw = e;
#pragma unroll
  for (int d = 1; d < 16; d <<= 1) {
    sx += __shfl_xor(sx, d, 16);
    sy += __shfl_xor(sy, d, 16);
    sz += __shfl_xor(sz, d, 16);
    sw += __shfl_xor(sw, d, 16);
  }
  if ((lane & 31) < 3) {
    int c = lane & 31;
    float rz = 1.0f / sw;
    float r = (c == 0) ? sx : ((c == 1) ? sy : sz);
    out[(b * 3 + c) * M + q] = r * rz;
  }
}

extern "C" void kernel_launch(void* const* d_in, const int* in_sizes, int n_in,
                              void* d_out, int out_size, void* d_ws, size_t ws_size,
                              hipStream_t stream) {
  const int B = 8, N = 8192, M = 2048;
  const float* pc = (const float*)d_in[0];
  const float* qc = (const float*)d_in[1];
  const float* temp = (const float*)d_in[2];
  float* out = (float*)d_out;

  size_t packBytes = (size_t)B * N * sizeof(float4);
  bool packed = (ws_size >= packBytes) && (d_ws != nullptr);

  int nblocks = (B * M) / 8;  // 8 queries per 256-thread block (2 per wave)
  if (packed) {
    prep_pack<<<dim3((B * N + 255) / 256), dim3(256), 0, stream>>>(
        pc, (float4*)d_ws, B, N);
    knn_project2<true><<<dim3(nblocks), dim3(256), 0, stream>>>(
        pc, qc, temp, (const float4*)d_ws, out, B, N, M);
  } else {
    knn_project2<false><<<dim3(nblocks), dim3(256), 0, stream>>>(
        pc, qc, temp, nullptr, out, B, N, M);
  }
}

// Round 3
// 105.385 us; speedup vs baseline: 1.9784x; 1.3752x over previous
//
#include <hip/hip_runtime.h>
#include <stdint.h>

typedef unsigned long long u64;
typedef unsigned int u32;

// ---- cross-lane helpers (VALU-pipe, no LDS except bpermute) ----
__device__ __forceinline__ float dpp_shr1_f(float v, int fill_bits) {
  // within each 16-lane row: lane i <- lane i-1; row-lead takes fill
  return __int_as_float(__builtin_amdgcn_update_dpp(
      fill_bits, __float_as_int(v), 0x111 /*row_shr:1*/, 0xF, 0xF, false));
}
__device__ __forceinline__ int dpp_shr1_i(int v) {
  return __builtin_amdgcn_update_dpp(0, v, 0x111, 0xF, 0xF, false);
}
__device__ __forceinline__ float rdlane_f(float v, int lane) {
  return __int_as_float(__builtin_amdgcn_readlane(__float_as_int(v), lane));
}

__global__ void prep_pack(const float* __restrict__ pc, float4* __restrict__ pp,
                          int B, int N) {
  int i = blockIdx.x * blockDim.x + threadIdx.x;
  if (i >= B * N) return;
  int b = i / N, n = i - b * N;
  float x = pc[(b * 3 + 0) * N + n];
  float y = pc[(b * 3 + 1) * N + n];
  float z = pc[(b * 3 + 2) * N + n];
  // pn in numpy order: (x*x + y*y) + z*z, no contraction
  float pn = __fadd_rn(__fadd_rn(__fmul_rn(x, x), __fmul_rn(y, y)), __fmul_rn(z, z));
  // store -2*coord (exact scaling) so q·(-2p) == -2*inner bit-exactly
  pp[i] = make_float4(__fmul_rn(x, -2.0f), __fmul_rn(y, -2.0f),
                      __fmul_rn(z, -2.0f), pn);
}

template <bool PACKED>
__global__ __launch_bounds__(256, 8) void knn_project3(
    const float* __restrict__ pc,    // (B,3,N)
    const float* __restrict__ qc,    // (B,3,M)
    const float* __restrict__ temp,  // scalar
    const float4* __restrict__ pp,   // packed (B,N): -2x,-2y,-2z,|p|^2
    float* __restrict__ out,         // (B,3,M)
    int B, int N, int M) {
  const float INF = __int_as_float(0x7f800000);
  const int NINF_BITS = (int)0xff800000;

  int tid = threadIdx.x;
  int lane = tid & 63;
  int grp = lane >> 5;   // which of the wave's two queries
  int sub = lane & 31;   // point slot within a 32-point batch
  int qid = blockIdx.x * 8 + (tid >> 5);
  int b = qid / M;
  int q = qid - b * M;

  float qx = qc[(b * 3 + 0) * M + q];
  float qy = qc[(b * 3 + 1) * M + q];
  float qz = qc[(b * 3 + 2) * M + q];
  float qn = __fadd_rn(__fadd_rn(__fmul_rn(qx, qx), __fmul_rn(qy, qy)),
                       __fmul_rn(qz, qz));

  // distributed top-16: lane (l&15) of each row holds entry (l&15), ascending.
  // rows 0,1 mirror query A; rows 2,3 mirror query B.
  float val = INF;
  int idx = 0;
  float thresh = INF;
  int bperm_addr = ((lane < 32) ? 15 : 47) << 2;  // row-15 entry of own group

  const float4* __restrict__ pb = pp + (size_t)b * N + sub;
  const float* __restrict__ pcb = pc + (size_t)b * 3 * N;

  auto PROC = [&](float4 c, int gpos) {
    // d2 = (qn+pn) + (qx*(-2px)+qy*(-2py)+qz*(-2pz))  == ref bit-exactly
    float s1 = __fmul_rn(qx, c.x);
    float s2 = __fmul_rn(qy, c.y);
    float s3 = __fmul_rn(qz, c.z);
    float t = __fadd_rn(__fadd_rn(s1, s2), s3);
    float d2 = __fadd_rn(__fadd_rn(qn, c.w), t);
    u64 mask = __ballot(d2 < thresh);
    if (mask) {
      u32 mlo = (u32)mask;          // query A candidates (lanes 0-31)
      u32 mhi = (u32)(mask >> 32);  // query B candidates (lanes 32-63)
      while (mlo | mhi) {
        int sA = __ffs(mlo) - 1;    // ascending index = top_k tie-break
        int sB = __ffs(mhi) - 1;
        int lA = (sA < 0) ? 0 : sA;
        int lB = (sB < 0) ? 32 : (sB + 32);
        float cA = rdlane_f(d2, lA);
        float cB = rdlane_f(d2, lB);
        if (sA < 0) cA = INF;
        if (sB < 0) cB = INF;
        int ciA = gpos + lA;
        int ciB = gpos + (lB - 32);
        float cv = grp ? cB : cA;
        int ci = grp ? ciB : ciA;
        // distributed sorted insert (strict < keeps stability)
        float pv = dpp_shr1_f(val, NINF_BITS);
        int pi = dpp_shr1_i(idx);
        bool p = cv < val;
        bool p2 = cv < pv;
        val = p ? (p2 ? pv : cv) : val;
        idx = p ? (p2 ? pi : ci) : idx;
        if (mlo) mlo &= mlo - 1;
        if (mhi) mhi &= mhi - 1;
      }
      // refresh threshold = own group's entry 15 (LDS pipe, not VALU)
      thresh = __int_as_float(
          __builtin_amdgcn_ds_bpermute(bperm_addr, __float_as_int(val)));
    }
  };

  if (PACKED) {
    // 64 iterations of 128 points, manually 2x-unrolled double buffer
    float4 a0 = pb[0], a1 = pb[32], a2 = pb[64], a3 = pb[96];
#pragma unroll 1
    for (int it = 0; it < 64; it += 2) {
      int o1 = (it + 1) * 128;
      float4 b0 = pb[o1], b1 = pb[o1 + 32], b2 = pb[o1 + 64], b3 = pb[o1 + 96];
      int o0 = it * 128;
      PROC(a0, o0); PROC(a1, o0 + 32); PROC(a2, o0 + 64); PROC(a3, o0 + 96);
      int o2 = ((it + 2) & 63) * 128;  // last prefetch wraps to 0 (harmless)
      a0 = pb[o2]; a1 = pb[o2 + 32]; a2 = pb[o2 + 64]; a3 = pb[o2 + 96];
      PROC(b0, o1); PROC(b1, o1 + 32); PROC(b2, o1 + 64); PROC(b3, o1 + 96);
    }
  } else {
#pragma unroll 1
    for (int g = 0; g < N; g += 32) {
      int n = g + sub;
      float x = pcb[n], y = pcb[N + n], z = pcb[2 * N + n];
      float pn = __fadd_rn(__fadd_rn(__fmul_rn(x, x), __fmul_rn(y, y)),
                           __fmul_rn(z, z));
      float4 c = make_float4(__fmul_rn(x, -2.0f), __fmul_rn(y, -2.0f),
                             __fmul_rn(z, -2.0f), pn);
      PROC(c, g);
    }
  }

  // ---- finisher: lane (l&15) owns entry (l&15); np-faithful arithmetic ----
  float Tv = temp[0];
  float sigma = fmaxf(__fmul_rn(Tv, Tv), 1e-4f);
  float sp = __fadd_rn(sigma, 1e-8f);
  int n = idx;
  float px = pcb[n], py = pcb[N + n], pz = pcb[2 * N + n];
  float dx = __fsub_rn(px, qx), dy = __fsub_rn(py, qy), dz = __fsub_rn(pz, qz);
  float d2w = __fadd_rn(__fadd_rn(__fmul_rn(dx, dx), __fmul_rn(dy, dy)),
                        __fmul_rn(dz, dz));
  float a = -__fdiv_rn(d2w, sp);                     // -dist
  float m = grp ? rdlane_f(a, 32) : rdlane_f(a, 0);  // max = entry 0 (sorted)
  float e = expf(__fsub_rn(a, m));
  float Z = e;
#pragma unroll
  for (int d = 1; d < 16; d <<= 1) Z += __shfl_xor(Z, d, 16);
  float w = __fdiv_rn(e, Z);                         // normalized weight
  float sx = __fmul_rn(px, w), sy = __fmul_rn(py, w), sz = __fmul_rn(pz, w);
#pragma unroll
  for (int d = 1; d < 16; d <<= 1) {
    sx += __shfl_xor(sx, d, 16);
    sy += __shfl_xor(sy, d, 16);
    sz += __shfl_xor(sz, d, 16);
  }
  if ((lane & 31) < 3) {
    int c = lane & 31;
    float r = (c == 0) ? sx : ((c == 1) ? sy : sz);
    out[(b * 3 + c) * M + q] = r;
  }
}

extern "C" void kernel_launch(void* const* d_in, const int* in_sizes, int n_in,
                              void* d_out, int out_size, void* d_ws, size_t ws_size,
                              hipStream_t stream) {
  const int B = 8, N = 8192, M = 2048;
  const float* pc = (const float*)d_in[0];
  const float* qc = (const float*)d_in[1];
  const float* temp = (const float*)d_in[2];
  float* out = (float*)d_out;

  size_t packBytes = (size_t)B * N * sizeof(float4);
  bool packed = (ws_size >= packBytes) && (d_ws != nullptr);

  int nblocks = (B * M) / 8;  // 8 queries / 256-thread block (2 per wave)
  if (packed) {
    prep_pack<<<dim3((B * N + 255) / 256), dim3(256), 0, stream>>>(
        pc, (float4*)d_ws, B, N);
    knn_project3<true><<<dim3(nblocks), dim3(256), 0, stream>>>(
        pc, qc, temp, (const float4*)d_ws, out, B, N, M);
  } else {
    knn_project3<false><<<dim3(nblocks), dim3(256), 0, stream>>>(
        pc, qc, temp, nullptr, out, B, N, M);
  }
}